// Round 14
// baseline (35.706 us; speedup 1.0000x reference)
//
#include <hip/hip_runtime.h>
#include <math.h>

// SphericalBessel — LDS-free, barrier-free, lane-owns-mode structure.
// Grid-stride STRIDE ≡ 0 (mod 100) -> each thread's kk = g%100 is FIXED for the
// whole kernel: its l, closed-form coeffs (kv pre-folded; inner is linear in them)
// and xcut live in VGPRs (loaded once). Unified branchless body for ALL l (0..9):
//   arg = r*k/(2pi); argc = max(arg,xc); w = rcp(argc); y = w^2
//   inner = s*(SG(y)*ws) + c*(GM(y)*wc),  ws=odd?w:1, wc=odd?1:w
//   out   = w*inner            (zero-padded deg-4 Horner pairs, exact for all l)
// Same validated w-space math as R10-R13 (absmax 0.0039). Stores: 4B/lane,
// wave = 256B contiguous, grid-step = dense 3.3MB slab. No ds ops, no phases:
// store issue is naturally smeared (1 per ~23 instrs), waves fully independent.

static constexpr double PI_D   = 3.14159265358979323846;
static constexpr double BETA_D = 1.0 / (2.0 * PI_D);
static constexpr double S2PI_D = 0.79788456080286535588;

__device__ __forceinline__ float rcpf(float x) { return __builtin_amdgcn_rcpf(x); }
__device__ __forceinline__ float sin_rev(float a) { float r; asm("v_sin_f32 %0, %1" : "=v"(r) : "v"(a)); return r; }
__device__ __forceinline__ float cos_rev(float a) { float r; asm("v_cos_f32 %0, %1" : "=v"(r) : "v"(a)); return r; }

// per-l table: [sg deg4..deg0 (5), gm deg4..deg0 (5), xcut_rev, pad] -- 10 x 12 f32.
// sg/gm are the R4-verified closed-form integer polys, scaled by S2PI*beta^e
// (odd l: e_sg = 2deg+2, e_gm = 2deg+1; even l: e_sg = 2deg+1, e_gm = 2deg+2),
// zero-padded at the high-degree end (Horner with fmaf(0,y,c)=c is exact).
struct CTab { float v[10][12]; };

constexpr CTab make_ctab() {
  CTab t{};
  constexpr double sgz[10][5] = {
    {0,0,0,0,1}, {0,0,0,0,1}, {0,0,0,3,-1}, {0,0,0,15,-6}, {0,0,105,-45,1},
    {0,0,945,-420,15}, {0,10395,-4725,210,-1}, {0,135135,-62370,3150,-28},
    {2027025,-945945,51975,-630,1}, {34459425,-16216200,945945,-13860,45}};
  constexpr double gmz[10][5] = {
    {0,0,0,0,0}, {0,0,0,0,-1}, {0,0,0,0,-3}, {0,0,0,-15,1}, {0,0,0,-105,10},
    {0,0,-945,105,-1}, {0,0,-10395,1260,-21}, {0,-135135,17325,-378,1},
    {0,-2027025,270270,-6930,36}, {-34459425,4729725,-135135,990,-1}};
  constexpr double XT[10] = {0,0,0.088,0.29,0.61,1.01,1.48,2.00,2.55,3.14};
  for (int l = 0; l < 10; ++l) {
    for (int i = 0; i < 5; ++i) {
      int deg = 4 - i;
      int es = (l & 1) ? (2*deg + 2) : (2*deg + 1);
      int eg = (l & 1) ? (2*deg + 1) : (2*deg + 2);
      double ss = S2PI_D; for (int q = 0; q < es; ++q) ss *= BETA_D;
      double sv = S2PI_D; for (int q = 0; q < eg; ++q) sv *= BETA_D;
      t.v[l][i]     = (float)(ss * sgz[l][i]);
      t.v[l][5 + i] = (float)(sv * gmz[l][i]);
    }
    t.v[l][10] = (float)(XT[l] * BETA_D);
    t.v[l][11] = 0.f;
  }
  return t;
}

__device__ __constant__ CTab CT = make_ctab();

__global__ __launch_bounds__(256) void sbf_kernel(const float* __restrict__ r,
                                                  const float* __restrict__ kvec,
                                                  float* __restrict__ out,
                                                  int steps, int stride) {
  const int g = blockIdx.x * 256 + threadIdx.x;
  // fixed per-thread mode
  unsigned kk = (unsigned)g % 100u;             // magic-mul
  int l = (int)sqrtf((float)kk);
  if ((l + 1) * (l + 1) <= (int)kk) ++l;        // guard sqrt rounding
  if (l * l > (int)kk) --l;
  const float* cv = CT.v[l];
  float kv  = kvec[kk];
  float kvb = kv * (float)BETA_D;
  // fold kv into the (linear) coefficient set -> epilogue is just w*inner
  float sg0 = cv[0]*kv, sg1 = cv[1]*kv, sg2 = cv[2]*kv, sg3 = cv[3]*kv, sg4 = cv[4]*kv;
  float gm0 = cv[5]*kv, gm1 = cv[6]*kv, gm2 = cv[7]*kv, gm3 = cv[8]*kv, gm4 = cv[9]*kv;
  float xc  = cv[10];
  const bool odd = (l & 1) != 0;                // loop-invariant -> one v_cmp, mask reused
  const int rstep = stride / 100;               // stride % 100 == 0 by construction
  const float* rp = r + ((unsigned)g / 100u);
  float* op = out + g;
  for (int it = 0; it < steps; ++it) {
    float rv   = *rp;                           // <=2 lines/wave, L1/L2-resident
    float arg  = rv * kvb;                      // x in revolutions
    float argc = fmaxf(arg, xc);                // clamp tail: j_l(xcut), |err|<=4e-3
    float w = rcpf(argc);
    float s = sin_rev(argc), c = cos_rev(argc);
    float y = w * w;
    float sgv = fmaf(fmaf(fmaf(fmaf(sg0, y, sg1), y, sg2), y, sg3), y, sg4);
    float gmv = fmaf(fmaf(fmaf(fmaf(gm0, y, gm1), y, gm2), y, gm3), y, gm4);
    float ws = odd ? w : 1.0f;                  // cndmask (saved mask)
    float wc = odd ? 1.0f : w;
    float inner = fmaf(s, sgv * ws, c * (gmv * wc));
    *op = w * inner;                            // 4B/lane, wave = 256B contiguous
    rp += rstep; op += stride;
  }
}

extern "C" void kernel_launch(void* const* d_in, const int* in_sizes, int n_in,
                              void* d_out, int out_size, void* d_ws, size_t ws_size,
                              hipStream_t stream) {
  const float* r = (const float*)d_in[0];
  const float* k = (const float*)d_in[1];
  float* out = (float*)d_out;
  const int G = 3200;                  // 256*G = 819200 ≡ 0 (mod 100)
  int stride = G * 256;
  int steps = out_size / stride;       // 26,214,400 / 819,200 = 32 exactly
  sbf_kernel<<<G, 256, 0, stream>>>(r, k, out, steps, stride);
}

// Round 15
// 29.560 us; speedup vs baseline: 1.2079x; 1.2079x over previous
//
#include <hip/hip_runtime.h>
#include <math.h>

// SphericalBessel — barrier-free wave-independent pipelines.
// Each 64-thread block (= ONE wave) owns a 64-n tile and computes all 100 modes
// itself in two kk-halves (0..51, 52..99), staging each half in LDS [64][W]
// (W=52/48, 13.3 KB total -> 12 waves/CU) and flushing with private float4
// stores. NO __syncthreads anywhere: intra-wave LDS ordering is automatic, and
// 12 independent wave-pipelines per CU drift apart -> continuous store issue
// (tests the "block-wide barriers phase-lock stores into bursts" theory for the
// 24.5us plateau). Mode math identical to R10/R13 (validated, absmax 0.0039).

static constexpr double PI_D   = 3.14159265358979323846;
static constexpr double BETA_D = 1.0 / (2.0 * PI_D);
static constexpr double S2PI_D = 0.79788456080286535588;

__device__ __forceinline__ float rcpf(float x) { return __builtin_amdgcn_rcpf(x); }
__device__ __forceinline__ float sin_rev(float a) { float r; asm("v_sin_f32 %0, %1" : "=v"(r) : "v"(a)); return r; }
__device__ __forceinline__ float cos_rev(float a) { float r; asm("v_cos_f32 %0, %1" : "=v"(r) : "v"(a)); return r; }

// raw integer closed-form z-polys (z = 1/x^2), highest degree first (R4-verified)
template<int L> struct ZC;
template<> struct ZC<2>{ static constexpr double sg[2]={3,-1};                              static constexpr double gm[1]={-3}; };
template<> struct ZC<3>{ static constexpr double sg[2]={15,-6};                             static constexpr double gm[2]={-15,1}; };
template<> struct ZC<4>{ static constexpr double sg[3]={105,-45,1};                         static constexpr double gm[2]={-105,10}; };
template<> struct ZC<5>{ static constexpr double sg[3]={945,-420,15};                       static constexpr double gm[3]={-945,105,-1}; };
template<> struct ZC<6>{ static constexpr double sg[4]={10395,-4725,210,-1};                static constexpr double gm[3]={-10395,1260,-21}; };
template<> struct ZC<7>{ static constexpr double sg[4]={135135,-62370,3150,-28};            static constexpr double gm[4]={-135135,17325,-378,1}; };
template<> struct ZC<8>{ static constexpr double sg[5]={2027025,-945945,51975,-630,1};      static constexpr double gm[4]={-2027025,270270,-6930,36}; };
template<> struct ZC<9>{ static constexpr double sg[5]={34459425,-16216200,945945,-13860,45}; static constexpr double gm[5]={-34459425,4729725,-135135,990,-1}; };

// w-space scaled coefficients (R10-validated): out = (kv*w) * inner, w = rcp(arg),
// arg = x/(2pi);  odd L: inner = s*w*SG(y) + c*GM(y);  even L: inner = c*w*GM(y) + s*SG(y)
template<int L> struct WC {
  static constexpr int NS = L / 2 + 1, NG = (L + 1) / 2;
  float sg[NS], gm[NG], xc;
  constexpr WC() : sg{}, gm{}, xc(0.f) {
    constexpr double XT[10] = {0,0,0.088,0.29,0.61,1.01,1.48,2.00,2.55,3.14};
    for (int i = 0; i < NS; ++i) {
      int deg = NS - 1 - i, e = (L & 1) ? (2*deg + 2) : (2*deg + 1);
      double s = S2PI_D; for (int t = 0; t < e; ++t) s *= BETA_D;
      sg[i] = (float)(s * ZC<L>::sg[i]);
    }
    for (int i = 0; i < NG; ++i) {
      int deg = NG - 1 - i, e = (L & 1) ? (2*deg + 1) : (2*deg + 2);
      double s = S2PI_D; for (int t = 0; t < e; ++t) s *= BETA_D;
      gm[i] = (float)(s * ZC<L>::gm[i]);
    }
    xc = (float)(XT[L] * BETA_D);
  }
};

template<int N>
__device__ __forceinline__ float polyH(float y, const float (&a)[N]) {
  float h = a[0];
#pragma unroll
  for (int i = 1; i < N; ++i) h = fmaf(h, y, a[i]);
  return h;
}

template<int L>
__device__ __forceinline__ float mode_val(float rvb, float kv) {
  float arg = rvb * kv;                // x in revolutions
  if constexpr (L == 0) {
    float w = rcpf(arg);
    return (sin_rev(arg) * (float)(S2PI_D * BETA_D)) * (kv * w);
  } else if constexpr (L == 1) {
    float w = rcpf(arg);
    float s = sin_rev(arg), c = cos_rev(arg);
    float inner = fmaf(s * w, (float)(S2PI_D * BETA_D * BETA_D),
                       -(c * (float)(S2PI_D * BETA_D)));
    return (kv * w) * inner;
  } else {
    constexpr WC<L> wc{};
    float argc = fmaxf(arg, wc.xc);    // clamp tail: j_l(xcut), |err|<=4e-3
    float w = rcpf(argc);
    float s = sin_rev(argc), c = cos_rev(argc);
    float y = w * w;
    float sgv = polyH(y, wc.sg);
    float gmv = polyH(y, wc.gm);
    float inner;
    if constexpr (L & 1) inner = fmaf(s * w, sgv, c * gmv);
    else                 inner = fmaf(c * w, gmv, s * sgv);
    return (kv * w) * inner;
  }
}

// modes [MLO,MHI) of group L into LDS row at column (L*L + m - KKB)
template<int L, int MLO, int MHI, int KKB>
__device__ __forceinline__ void do_lr(float rvb, const float* __restrict__ kvec,
                                      float* rowbase) {
#pragma unroll
  for (int m = MLO; m < MHI; ++m) {
    const int KK = L * L + m;
    rowbase[KK - KKB] = mode_val<L>(rvb, kvec[KK]);   // kv uniform -> s_load
  }
}

// flush a [64][W] LDS half-tile to out rows (global row stride 100, col base CB)
template<int W, int CB, int ROUNDS>
__device__ __forceinline__ void flushW(const float* __restrict__ lds,
                                       float* __restrict__ outrow, int lane) {
  int e = lane * 4;
  int n = e / W;                        // compile-time W -> magic-mul
  int c = e - n * W;
  const float* lp = lds + e;            // LDS is flat-contiguous; 16B aligned
  float* gp = outrow + n * 100 + CB + c;
  constexpr int DN = 256 / W, DC = 256 % W;
#pragma unroll
  for (int rnd = 0; rnd < ROUNDS; ++rnd) {
    float4 v = *reinterpret_cast<const float4*>(lp);
    *reinterpret_cast<float4*>(gp) = v; // 16B aligned: c,CB,rows all = 0 mod 4
    lp += 256;
    c += DC;
    bool carry = (c >= W);
    c = carry ? (c - W) : c;
    gp += DN * 100 + DC + (carry ? (100 - W) : 0);
  }
}

__global__ __launch_bounds__(64) void sbf_kernel(const float* __restrict__ r,
                                                 const float* __restrict__ kvec,
                                                 float* __restrict__ out) {
  __shared__ float lds[64 * 52];        // 13312 B -> 12 waves/CU
  const int lane = threadIdx.x;
  const int n0 = blockIdx.x * 64;
  float rvb = r[n0 + lane] * (float)BETA_D;
  float* outrow = out + (size_t)n0 * 100;

  // half A: kk 0..51 = l 0..6 full + l7 m0..2; LDS row stride 52
  {
    float* rowbase = lds + lane * 52;
    do_lr<0, 0,  1, 0>(rvb, kvec, rowbase);
    do_lr<1, 0,  3, 0>(rvb, kvec, rowbase);
    do_lr<2, 0,  5, 0>(rvb, kvec, rowbase);
    do_lr<3, 0,  7, 0>(rvb, kvec, rowbase);
    do_lr<4, 0,  9, 0>(rvb, kvec, rowbase);
    do_lr<5, 0, 11, 0>(rvb, kvec, rowbase);
    do_lr<6, 0, 13, 0>(rvb, kvec, rowbase);
    do_lr<7, 0,  3, 0>(rvb, kvec, rowbase);
    flushW<52, 0, 13>(lds, outrow, lane);   // 3328 floats; stores fire-and-forget
  }
  // half B: kk 52..99 = l7 m3..14 + l8,l9 full; LDS row stride 48
  // (intra-wave lgkmcnt orders the WAR on lds; half-A stores drain under this compute)
  {
    float* rowbase = lds + lane * 48;
    do_lr<7, 3, 15, 52>(rvb, kvec, rowbase);
    do_lr<8, 0, 17, 52>(rvb, kvec, rowbase);
    do_lr<9, 0, 19, 52>(rvb, kvec, rowbase);
    flushW<48, 52, 12>(lds, outrow, lane);  // 3072 floats
  }
}

extern "C" void kernel_launch(void* const* d_in, const int* in_sizes, int n_in,
                              void* d_out, int out_size, void* d_ws, size_t ws_size,
                              hipStream_t stream) {
  const float* r = (const float*)d_in[0];
  const float* k = (const float*)d_in[1];
  float* out = (float*)d_out;
  int N = in_sizes[0];                  // 262144
  int blocks = N / 64;                  // 4096 one-wave blocks
  sbf_kernel<<<blocks, 64, 0, stream>>>(r, k, out);
}